// Round 14
// baseline (276.468 us; speedup 1.0000x reference)
//
#include <hip/hip_runtime.h>

// LDPC BP decoder, (3,6)-regular — fused full-chip version, 2 CNs/thread.
// Edge e (vn order) = 3v+j; c = e mod 8192, t = e div 8192, e = c + 8192t.
//
// r13 -> r14: cn_fused processes TWO check nodes per thread (c, c+4096).
// Doubles independent f64 phi chains + memory-level parallelism per wave;
// grid 2048 blocks = one full-occupancy cohort (8 blocks/CU). Math chain
// bit-identical to r13 (absmax must stay exactly 0.25).

constexpr int NUM_VNS   = 16384;
constexpr int NUM_CNS   = 8192;
constexpr int NUM_EDGES = 49152;
constexpr int BATCH     = 128;
constexpr int NUM_ITER  = 8;
constexpr float LLR_MAX = 20.0f;
constexpr float PHI_MIN = 8.5e-8f;
constexpr float PHI_MAX = 16.635532f;

// exp(x) for x in [0, 16.64]; internal rel err ~2^-42.
__device__ __forceinline__ double lean_exp(double x) {
    double t = x * 1.4426950408889634;
    double k = __builtin_rint(t);
    double r = __builtin_fma(-k, 0.6931471805599453, x);
    r = __builtin_fma(-k, 2.3190468138462996e-17, r);
    double p = 1.0 / 3628800.0;                  // Taylor deg 10, |r|<=0.347
    p = __builtin_fma(p, r, 1.0 / 362880.0);
    p = __builtin_fma(p, r, 1.0 / 40320.0);
    p = __builtin_fma(p, r, 1.0 / 5040.0);
    p = __builtin_fma(p, r, 1.0 / 720.0);
    p = __builtin_fma(p, r, 1.0 / 120.0);
    p = __builtin_fma(p, r, 1.0 / 24.0);
    p = __builtin_fma(p, r, 1.0 / 6.0);
    p = __builtin_fma(p, r, 0.5);
    p = __builtin_fma(p, r, 1.0);
    p = __builtin_fma(p, r, 1.0);
    int ik = (int)k;                              // k in [0,24]
    double s = __hiloint2double((1023 + ik) << 20, 0);
    return p * s;
}

// log(v) for v in [2^-23, 2^25], v an exact f32 value; abs err ~2^-40.
__device__ __forceinline__ double lean_log(double v) {
    int hv = __double2hiint(v);
    int lv = __double2loint(v);
    int e  = (hv >> 20) - 1023;
    double m = __hiloint2double((hv & 0x000FFFFF) | 0x3FF00000, lv);
    if (m >= 1.4142135623730951) { m *= 0.5; e += 1; }   // m in [0.7071,1.4142)
    double t = m - 1.0;
    double d = t + 2.0;
    double r = (double)__builtin_amdgcn_rcpf((float)d);
    r = __builtin_fma(__builtin_fma(-d, r, 1.0), r, r);
    double u = t * r;
    double w = u * u;                             // w <= 0.0295
    double P = 2.0 / 13.0;                        // 2*artanh: deg 6 in w
    P = __builtin_fma(P, w, 2.0 / 11.0);
    P = __builtin_fma(P, w, 2.0 / 9.0);
    P = __builtin_fma(P, w, 2.0 / 7.0);
    P = __builtin_fma(P, w, 2.0 / 5.0);
    P = __builtin_fma(P, w, 2.0 / 3.0);
    P = __builtin_fma(P, w, 2.0);
    double lm = u * P;
    return __builtin_fma((double)e, 0.6931471805599453, lm);
}

// literal reference chain: clip; ex=f32(exp); a=ex+1, b=ex-1 in f32;
// la=f32(log a), lb=f32(log b); return la-lb.
__device__ __forceinline__ float phi_f(float xf) {
    xf = fminf(fmaxf(xf, PHI_MIN), PHI_MAX);
    float exf = (float)lean_exp((double)xf);
    float af = exf + 1.0f;
    float bf = exf - 1.0f;
    float la = (float)lean_log((double)af);
    float lb = (float)lean_log((double)bf);
    return la - lb;
}

// ---- fused CN kernel, 2 CNs per thread: c and c+4096. ----
template<int FIRST>
__global__ __launch_bounds__(256)
void cn_fused2(const float* __restrict__ llr, const float* __restrict__ msgIn,
               float* __restrict__ msgOut)
{
    int gid = blockIdx.x * 256 + threadIdx.x;       // b*4096 + ch
    int b  = gid >> 12;
    int ch = gid & 4095;
    const float* mi = msgIn + (size_t)b * NUM_EDGES;
    float* mo = msgOut + (size_t)b * NUM_EDGES;
    const float* lbp = llr + (size_t)b * NUM_VNS;

    float g0[6], g1[6];                             // signed mags (sign in bit)
#pragma unroll
    for (int t = 0; t < 6; ++t) {
#pragma unroll
        for (int h = 0; h < 2; ++h) {
            int c = ch + (h ? 4096 : 0);
            int e = c + (t << 13);
            int v = (int)(((unsigned)e * 43691u) >> 17);  // e/3, e < 131072
            float x = fminf(fmaxf(lbp[v], -LLR_MAX), LLR_MAX);
            float m;
            if (FIRST) {
                m = -x;                                   // msgs are all zero
            } else {
                int e0 = 3 * v;
                float s = ((mi[e0] + mi[e0 + 1]) + mi[e0 + 2]) - x;  // exact order
                m = s - mi[e];                            // vn-extrinsic
            }
            unsigned neg = (m < 0.0f) ? 0x80000000u : 0u; // sign(0) -> +1
            float mg = phi_f(fabsf(m));
            float sm = __uint_as_float(__float_as_uint(mg) | neg);
            if (h) g1[t] = sm; else g0[t] = sm;
        }
    }
#pragma unroll
    for (int h = 0; h < 2; ++h) {
        float* g = h ? g1 : g0;
        int c = ch + (h ? 4096 : 0);
        float a0 = fabsf(g[0]), a1 = fabsf(g[1]), a2 = fabsf(g[2]);
        float a3 = fabsf(g[3]), a4 = fabsf(g[4]), a5 = fabsf(g[5]);
        float ms = ((((a0 + a1) + a2) + a3) + a4) + a5;   // reference left-fold
        unsigned all6 = (__float_as_uint(g[0]) ^ __float_as_uint(g[1])
                       ^ __float_as_uint(g[2]) ^ __float_as_uint(g[3])
                       ^ __float_as_uint(g[4]) ^ __float_as_uint(g[5]))
                      & 0x80000000u;
#pragma unroll
        for (int t = 0; t < 6; ++t) {
            int e = c + (t << 13);
            float o = phi_f(ms - fabsf(g[t]));
            unsigned sg = all6 ^ (__float_as_uint(g[t]) & 0x80000000u);
            mo[e] = __uint_as_float(__float_as_uint(o) ^ sg);
        }
    }
}

// ---- VN kernel (fallback phases + final marginalize). ----
template<int FIRST, int LAST>
__global__ __launch_bounds__(256)
void vn_kernel(const float* __restrict__ llr, const float* __restrict__ msg,
               float* __restrict__ outv)
{
    int gid = blockIdx.x * 256 + threadIdx.x;       // b*16384 + v
    int b = gid >> 14;
    int v = gid & 16383;
    float x = fminf(fmaxf(llr[gid], -LLR_MAX), LLR_MAX);
    float s;
    if (FIRST) {
        s = -x;
    } else {
        const float* mb = msg + (size_t)b * NUM_EDGES;
        int e = 3 * v;
        s = ((mb[e] + mb[e + 1]) + mb[e + 2]) - x;  // exact reference order
    }
    outv[gid] = LAST ? -s : s;
}

// ---- CN kernel (r12 fallback, reads precomputed vtot). ----
template<int FIRST>
__global__ __launch_bounds__(256)
void cn_kernel(float* __restrict__ msg, const float* __restrict__ vtot)
{
    int gid = blockIdx.x * 256 + threadIdx.x;       // b*8192 + c
    int b = gid >> 13;
    int c = gid & 8191;
    float* mb = msg + (size_t)b * NUM_EDGES;
    const float* vt = vtot + (size_t)b * NUM_VNS;

    float g[6];
#pragma unroll
    for (int t = 0; t < 6; ++t) {
        int e = c + (t << 13);
        int v = (int)(((unsigned)e * 43691u) >> 17);
        float m = FIRST ? vt[v] : (vt[v] - mb[e]);
        unsigned neg = (m < 0.0f) ? 0x80000000u : 0u;
        float mg = phi_f(fabsf(m));
        g[t] = __uint_as_float(__float_as_uint(mg) | neg);
    }
    float a0 = fabsf(g[0]), a1 = fabsf(g[1]), a2 = fabsf(g[2]);
    float a3 = fabsf(g[3]), a4 = fabsf(g[4]), a5 = fabsf(g[5]);
    float ms = ((((a0 + a1) + a2) + a3) + a4) + a5;
    unsigned all6 = (__float_as_uint(g[0]) ^ __float_as_uint(g[1])
                   ^ __float_as_uint(g[2]) ^ __float_as_uint(g[3])
                   ^ __float_as_uint(g[4]) ^ __float_as_uint(g[5]))
                  & 0x80000000u;
#pragma unroll
    for (int t = 0; t < 6; ++t) {
        int e = c + (t << 13);
        float o = phi_f(ms - fabsf(g[t]));
        unsigned sg = all6 ^ (__float_as_uint(g[t]) & 0x80000000u);
        mb[e] = __uint_as_float(__float_as_uint(o) ^ sg);
    }
}

extern "C" void kernel_launch(void* const* d_in, const int* in_sizes, int n_in,
                              void* d_out, int out_size, void* d_ws, size_t ws_size,
                              hipStream_t stream) {
    const float* llr = (const float*)d_in[0];
    float* out = (float*)d_out;

    const int VNB  = BATCH * NUM_VNS / 256;            // 8192 blocks
    const int CNB  = BATCH * NUM_CNS / 256;            // 4096 blocks
    const int CNB2 = BATCH * (NUM_CNS / 2) / 256;      // 2048 blocks
    const size_t MSGSZ = (size_t)BATCH * NUM_EDGES;    // 6.29M floats = 24 MB

    if (ws_size >= 2 * MSGSZ * sizeof(float)) {
        // ---- fused path: 8 CN launches (double-buffered) + final VN ----
        float* buf0 = (float*)d_ws;
        float* buf1 = buf0 + MSGSZ;
        cn_fused2<1><<<CNB2, 256, 0, stream>>>(llr, buf0, buf0);   // writes buf0
        for (int it = 1; it < NUM_ITER; ++it) {
            float* in  = (it & 1) ? buf0 : buf1;
            float* dst = (it & 1) ? buf1 : buf0;
            cn_fused2<0><<<CNB2, 256, 0, stream>>>(llr, in, dst);
        }
        // NUM_ITER=8: last write was buf1 (it=7 -> dst=buf1)
        vn_kernel<0, 1><<<VNB, 256, 0, stream>>>(llr, buf1, out);
    } else {
        // ---- r12 fallback: 32 MB workspace ----
        float* msg  = (float*)d_ws;
        float* vtot = msg + MSGSZ;
        vn_kernel<1, 0><<<VNB, 256, 0, stream>>>(llr, msg, vtot);
        cn_kernel<1><<<CNB, 256, 0, stream>>>(msg, vtot);
        for (int it = 1; it < NUM_ITER; ++it) {
            vn_kernel<0, 0><<<VNB, 256, 0, stream>>>(llr, msg, vtot);
            cn_kernel<0><<<CNB, 256, 0, stream>>>(msg, vtot);
        }
        vn_kernel<0, 1><<<VNB, 256, 0, stream>>>(llr, msg, out);
    }
}

// Round 15
// 273.714 us; speedup vs baseline: 1.0101x; 1.0101x over previous
//
#include <hip/hip_runtime.h>

// LDPC BP decoder, (3,6)-regular — fused full-chip version, XCD-sharded.
// Edge e (vn order) = 3v+j; c = e mod 8192, t = e div 8192, e = c + 8192t.
//
// r14 -> r15: (a) XCD-aware block remap — bid&7 selects XCD (round-robin
// dispatch); each XCD owns 16 whole batch elements, so the 24MB msg stream
// becomes a ~4MB per-XCD L2-resident working set, and iteration k's writes
// are iteration k+1's L2 hits. (b) own-edge message re-gather replaced by
// register select (mi[e] == one of mi[3v..3v+2]). (c) back to 1 CN/thread.
// Math chain bit-identical to r13/r14 (absmax must stay exactly 0.25).

constexpr int NUM_VNS   = 16384;
constexpr int NUM_CNS   = 8192;
constexpr int NUM_EDGES = 49152;
constexpr int BATCH     = 128;
constexpr int NUM_ITER  = 8;
constexpr float LLR_MAX = 20.0f;
constexpr float PHI_MIN = 8.5e-8f;
constexpr float PHI_MAX = 16.635532f;

// exp(x) for x in [0, 16.64]; internal rel err ~2^-42.
__device__ __forceinline__ double lean_exp(double x) {
    double t = x * 1.4426950408889634;
    double k = __builtin_rint(t);
    double r = __builtin_fma(-k, 0.6931471805599453, x);
    r = __builtin_fma(-k, 2.3190468138462996e-17, r);
    double p = 1.0 / 3628800.0;                  // Taylor deg 10, |r|<=0.347
    p = __builtin_fma(p, r, 1.0 / 362880.0);
    p = __builtin_fma(p, r, 1.0 / 40320.0);
    p = __builtin_fma(p, r, 1.0 / 5040.0);
    p = __builtin_fma(p, r, 1.0 / 720.0);
    p = __builtin_fma(p, r, 1.0 / 120.0);
    p = __builtin_fma(p, r, 1.0 / 24.0);
    p = __builtin_fma(p, r, 1.0 / 6.0);
    p = __builtin_fma(p, r, 0.5);
    p = __builtin_fma(p, r, 1.0);
    p = __builtin_fma(p, r, 1.0);
    int ik = (int)k;                              // k in [0,24]
    double s = __hiloint2double((1023 + ik) << 20, 0);
    return p * s;
}

// log(v) for v in [2^-23, 2^25], v an exact f32 value; abs err ~2^-40.
__device__ __forceinline__ double lean_log(double v) {
    int hv = __double2hiint(v);
    int lv = __double2loint(v);
    int e  = (hv >> 20) - 1023;
    double m = __hiloint2double((hv & 0x000FFFFF) | 0x3FF00000, lv);
    if (m >= 1.4142135623730951) { m *= 0.5; e += 1; }   // m in [0.7071,1.4142)
    double t = m - 1.0;
    double d = t + 2.0;
    double r = (double)__builtin_amdgcn_rcpf((float)d);
    r = __builtin_fma(__builtin_fma(-d, r, 1.0), r, r);
    double u = t * r;
    double w = u * u;                             // w <= 0.0295
    double P = 2.0 / 13.0;                        // 2*artanh: deg 6 in w
    P = __builtin_fma(P, w, 2.0 / 11.0);
    P = __builtin_fma(P, w, 2.0 / 9.0);
    P = __builtin_fma(P, w, 2.0 / 7.0);
    P = __builtin_fma(P, w, 2.0 / 5.0);
    P = __builtin_fma(P, w, 2.0 / 3.0);
    P = __builtin_fma(P, w, 2.0);
    double lm = u * P;
    return __builtin_fma((double)e, 0.6931471805599453, lm);
}

// literal reference chain: clip; ex=f32(exp); a=ex+1, b=ex-1 in f32;
// la=f32(log a), lb=f32(log b); return la-lb.
__device__ __forceinline__ float phi_f(float xf) {
    xf = fminf(fmaxf(xf, PHI_MIN), PHI_MAX);
    float exf = (float)lean_exp((double)xf);
    float af = exf + 1.0f;
    float bf = exf - 1.0f;
    float la = (float)lean_log((double)af);
    float lb = (float)lean_log((double)bf);
    return la - lb;
}

// ---- fused CN kernel, XCD-sharded: one thread per (b, c). ----
template<int FIRST>
__global__ __launch_bounds__(256)
void cn_fused(const float* __restrict__ llr, const float* __restrict__ msgIn,
              float* __restrict__ msgOut)
{
    // 4096 blocks: bid&7 = XCD (round-robin dispatch); each XCD owns 16
    // whole batches -> per-XCD L2-resident msg working set.
    int bid = blockIdx.x;
    int seq = bid >> 3;                          // [0, 512)
    int b   = (bid & 7) * 16 + (seq >> 5);       // 16 batches per XCD
    int c   = (seq & 31) * 256 + threadIdx.x;    // [0, 8192)

    const float* mi = msgIn + (size_t)b * NUM_EDGES;
    float* mo = msgOut + (size_t)b * NUM_EDGES;
    const float* lbp = llr + (size_t)b * NUM_VNS;

    float g[6];                                     // signed mags (sign in bit)
#pragma unroll
    for (int t = 0; t < 6; ++t) {
        int e = c + (t << 13);
        int v = (int)(((unsigned)e * 43691u) >> 17);  // e/3, e < 98304
        float x = fminf(fmaxf(lbp[v], -LLR_MAX), LLR_MAX);
        float m;
        if (FIRST) {
            m = -x;                                   // msgs are all zero
        } else {
            int e0 = 3 * v;
            int j  = e - e0;                          // e mod 3
            float m0 = mi[e0], m1 = mi[e0 + 1], m2 = mi[e0 + 2];
            float s = ((m0 + m1) + m2) - x;           // exact reference order
            float own = (j == 0) ? m0 : ((j == 1) ? m1 : m2);
            m = s - own;                              // vn-extrinsic
        }
        unsigned neg = (m < 0.0f) ? 0x80000000u : 0u; // sign(0) -> +1
        float mg = phi_f(fabsf(m));
        g[t] = __uint_as_float(__float_as_uint(mg) | neg);
    }
    float a0 = fabsf(g[0]), a1 = fabsf(g[1]), a2 = fabsf(g[2]);
    float a3 = fabsf(g[3]), a4 = fabsf(g[4]), a5 = fabsf(g[5]);
    float ms = ((((a0 + a1) + a2) + a3) + a4) + a5;   // reference left-fold
    unsigned all6 = (__float_as_uint(g[0]) ^ __float_as_uint(g[1])
                   ^ __float_as_uint(g[2]) ^ __float_as_uint(g[3])
                   ^ __float_as_uint(g[4]) ^ __float_as_uint(g[5]))
                  & 0x80000000u;
#pragma unroll
    for (int t = 0; t < 6; ++t) {
        int e = c + (t << 13);
        float o = phi_f(ms - fabsf(g[t]));
        unsigned sg = all6 ^ (__float_as_uint(g[t]) & 0x80000000u);
        mo[e] = __uint_as_float(__float_as_uint(o) ^ sg);
    }
}

// ---- final marginalize, XCD-sharded to match cn_fused's batch->XCD map. ----
__global__ __launch_bounds__(256)
void vn_final(const float* __restrict__ llr, const float* __restrict__ msg,
              float* __restrict__ outv)
{
    int bid = blockIdx.x;                        // 8192 blocks
    int seq = bid >> 3;                          // [0, 1024)
    int b   = (bid & 7) * 16 + (seq >> 6);       // 16 batches per XCD
    int v   = (seq & 63) * 256 + threadIdx.x;    // [0, 16384)
    float x = fminf(fmaxf(llr[(size_t)b * NUM_VNS + v], -LLR_MAX), LLR_MAX);
    const float* mb = msg + (size_t)b * NUM_EDGES;
    int e = 3 * v;
    float s = ((mb[e] + mb[e + 1]) + mb[e + 2]) - x;  // exact reference order
    outv[(size_t)b * NUM_VNS + v] = -s;
}

// ---- VN kernel (r12 fallback). ----
template<int FIRST, int LAST>
__global__ __launch_bounds__(256)
void vn_kernel(const float* __restrict__ llr, const float* __restrict__ msg,
               float* __restrict__ outv)
{
    int gid = blockIdx.x * 256 + threadIdx.x;       // b*16384 + v
    int b = gid >> 14;
    int v = gid & 16383;
    float x = fminf(fmaxf(llr[gid], -LLR_MAX), LLR_MAX);
    float s;
    if (FIRST) {
        s = -x;
    } else {
        const float* mb = msg + (size_t)b * NUM_EDGES;
        int e = 3 * v;
        s = ((mb[e] + mb[e + 1]) + mb[e + 2]) - x;
    }
    outv[gid] = LAST ? -s : s;
}

// ---- CN kernel (r12 fallback, reads precomputed vtot). ----
template<int FIRST>
__global__ __launch_bounds__(256)
void cn_kernel(float* __restrict__ msg, const float* __restrict__ vtot)
{
    int gid = blockIdx.x * 256 + threadIdx.x;       // b*8192 + c
    int b = gid >> 13;
    int c = gid & 8191;
    float* mb = msg + (size_t)b * NUM_EDGES;
    const float* vt = vtot + (size_t)b * NUM_VNS;

    float g[6];
#pragma unroll
    for (int t = 0; t < 6; ++t) {
        int e = c + (t << 13);
        int v = (int)(((unsigned)e * 43691u) >> 17);
        float m = FIRST ? vt[v] : (vt[v] - mb[e]);
        unsigned neg = (m < 0.0f) ? 0x80000000u : 0u;
        float mg = phi_f(fabsf(m));
        g[t] = __uint_as_float(__float_as_uint(mg) | neg);
    }
    float a0 = fabsf(g[0]), a1 = fabsf(g[1]), a2 = fabsf(g[2]);
    float a3 = fabsf(g[3]), a4 = fabsf(g[4]), a5 = fabsf(g[5]);
    float ms = ((((a0 + a1) + a2) + a3) + a4) + a5;
    unsigned all6 = (__float_as_uint(g[0]) ^ __float_as_uint(g[1])
                   ^ __float_as_uint(g[2]) ^ __float_as_uint(g[3])
                   ^ __float_as_uint(g[4]) ^ __float_as_uint(g[5]))
                  & 0x80000000u;
#pragma unroll
    for (int t = 0; t < 6; ++t) {
        int e = c + (t << 13);
        float o = phi_f(ms - fabsf(g[t]));
        unsigned sg = all6 ^ (__float_as_uint(g[t]) & 0x80000000u);
        mb[e] = __uint_as_float(__float_as_uint(o) ^ sg);
    }
}

extern "C" void kernel_launch(void* const* d_in, const int* in_sizes, int n_in,
                              void* d_out, int out_size, void* d_ws, size_t ws_size,
                              hipStream_t stream) {
    const float* llr = (const float*)d_in[0];
    float* out = (float*)d_out;

    const int VNB = BATCH * NUM_VNS / 256;             // 8192 blocks
    const int CNB = BATCH * NUM_CNS / 256;             // 4096 blocks
    const size_t MSGSZ = (size_t)BATCH * NUM_EDGES;    // 6.29M floats = 24 MB

    if (ws_size >= 2 * MSGSZ * sizeof(float)) {
        // ---- fused path: 8 CN launches (double-buffered) + final VN ----
        float* buf0 = (float*)d_ws;
        float* buf1 = buf0 + MSGSZ;
        cn_fused<1><<<CNB, 256, 0, stream>>>(llr, buf0, buf0);     // writes buf0
        for (int it = 1; it < NUM_ITER; ++it) {
            float* in  = (it & 1) ? buf0 : buf1;
            float* dst = (it & 1) ? buf1 : buf0;
            cn_fused<0><<<CNB, 256, 0, stream>>>(llr, in, dst);
        }
        // NUM_ITER=8: last write was buf1 (it=7 -> dst=buf1)
        vn_final<<<VNB, 256, 0, stream>>>(llr, buf1, out);
    } else {
        // ---- r12 fallback: 32 MB workspace ----
        float* msg  = (float*)d_ws;
        float* vtot = msg + MSGSZ;
        vn_kernel<1, 0><<<VNB, 256, 0, stream>>>(llr, msg, vtot);
        cn_kernel<1><<<CNB, 256, 0, stream>>>(msg, vtot);
        for (int it = 1; it < NUM_ITER; ++it) {
            vn_kernel<0, 0><<<VNB, 256, 0, stream>>>(llr, msg, vtot);
            cn_kernel<0><<<CNB, 256, 0, stream>>>(msg, vtot);
        }
        vn_kernel<0, 1><<<VNB, 256, 0, stream>>>(llr, msg, out);
    }
}

// Round 16
// 215.733 us; speedup vs baseline: 1.2815x; 1.2688x over previous
//
#include <hip/hip_runtime.h>

// LDPC BP decoder, (3,6)-regular — fused full-chip version, table-phi.
// Edge e (vn order) = 3v+j; c = e mod 8192, t = e div 8192, e = c + 8192t.
//
// r13-r15 lesson: CN launches are ~90% VALU-bound on f64 phi; ILP/locality/
// spill levers all neutral. r16: cut phi op count with LDS-table exp/log.
// Precision budget (from r10's failure mode): exp error must scale with x
// (deg-3 Taylor after 2^(1/32) reduction: err r^4/24, r<=0.0108, and r=x as
// x->0 -> error vanishes in the b=ex-1 cancellation zone); logs only need
// ~2^-31 abs (a rounding flip costs 1 ulp of the RESULT, ~2e-6, amplified
// ~300x -> ~6e-4 << 0.755 slack). Tables self-bootstrapped per block from
// the full-accuracy lean_exp/lean_log (kept for init + fallback kernels).

constexpr int NUM_VNS   = 16384;
constexpr int NUM_CNS   = 8192;
constexpr int NUM_EDGES = 49152;
constexpr int BATCH     = 128;
constexpr int NUM_ITER  = 8;
constexpr float LLR_MAX = 20.0f;
constexpr float PHI_MIN = 8.5e-8f;
constexpr float PHI_MAX = 16.635532f;

// ---- full-accuracy reference primitives (table init + fallback path) ----
// exp(x) for x in [0, 16.64]; internal rel err ~2^-42.
__device__ __forceinline__ double lean_exp(double x) {
    double t = x * 1.4426950408889634;
    double k = __builtin_rint(t);
    double r = __builtin_fma(-k, 0.6931471805599453, x);
    r = __builtin_fma(-k, 2.3190468138462996e-17, r);
    double p = 1.0 / 3628800.0;                  // Taylor deg 10, |r|<=0.347
    p = __builtin_fma(p, r, 1.0 / 362880.0);
    p = __builtin_fma(p, r, 1.0 / 40320.0);
    p = __builtin_fma(p, r, 1.0 / 5040.0);
    p = __builtin_fma(p, r, 1.0 / 720.0);
    p = __builtin_fma(p, r, 1.0 / 120.0);
    p = __builtin_fma(p, r, 1.0 / 24.0);
    p = __builtin_fma(p, r, 1.0 / 6.0);
    p = __builtin_fma(p, r, 0.5);
    p = __builtin_fma(p, r, 1.0);
    p = __builtin_fma(p, r, 1.0);
    int ik = (int)k;                              // k in [0,24]
    double s = __hiloint2double((1023 + ik) << 20, 0);
    return p * s;
}

// log(v) for v in [2^-23, 2^25], v an exact f32 value; abs err ~2^-40.
__device__ __forceinline__ double lean_log(double v) {
    int hv = __double2hiint(v);
    int lv = __double2loint(v);
    int e  = (hv >> 20) - 1023;
    double m = __hiloint2double((hv & 0x000FFFFF) | 0x3FF00000, lv);
    if (m >= 1.4142135623730951) { m *= 0.5; e += 1; }   // m in [0.7071,1.4142)
    double t = m - 1.0;
    double d = t + 2.0;
    double r = (double)__builtin_amdgcn_rcpf((float)d);
    r = __builtin_fma(__builtin_fma(-d, r, 1.0), r, r);
    double u = t * r;
    double w = u * u;                             // w <= 0.0295
    double P = 2.0 / 13.0;                        // 2*artanh: deg 6 in w
    P = __builtin_fma(P, w, 2.0 / 11.0);
    P = __builtin_fma(P, w, 2.0 / 9.0);
    P = __builtin_fma(P, w, 2.0 / 7.0);
    P = __builtin_fma(P, w, 2.0 / 5.0);
    P = __builtin_fma(P, w, 2.0 / 3.0);
    P = __builtin_fma(P, w, 2.0);
    double lm = u * P;
    return __builtin_fma((double)e, 0.6931471805599453, lm);
}

__device__ __forceinline__ float phi_f(float xf) {
    xf = fminf(fmaxf(xf, PHI_MIN), PHI_MAX);
    float exf = (float)lean_exp((double)xf);
    float af = exf + 1.0f;
    float bf = exf - 1.0f;
    float la = (float)lean_log((double)af);
    float lb = (float)lean_log((double)bf);
    return la - lb;
}

// ---- fast table primitives (main path) ----
constexpr double EXP_STEP = 0.021660849392498291;   // double(ln2/32)
constexpr double EXP_INV  = 46.166241308446828;     // 32/ln2

// e^x, x in [0, 16.64]; rel err <= r^4/24 ~ 2^-30.7, and -> 0 as x -> 0.
__device__ __forceinline__ double fast_exp(double x, const double* et) {
    double kd = __builtin_rint(x * EXP_INV);
    double r  = __builtin_fma(-kd, EXP_STEP, x);     // |r| <= 0.01083
    int n = (int)kd;                                 // [0, 768]
    double p = __builtin_fma(
        r, __builtin_fma(r, __builtin_fma(r, 1.0 / 6.0, 0.5), 1.0), 1.0);
    double s = et[n & 31];                           // 2^(j/32)
    int sh = __double2hiint(s) + ((n >> 5) << 20);   // * 2^k
    s = __hiloint2double(sh, __double2loint(s));
    return p * s;
}

// log(v), v an exact f32 in [2^-23, 2^25]; abs err ~2^-32.3.
__device__ __forceinline__ double fast_log(double v, const double* lt) {
    int hv = __double2hiint(v);
    int lv = __double2loint(v);
    int E  = (hv >> 20) - 1023;
    double m = __hiloint2double((hv & 0x000FFFFF) | 0x3FF00000, lv); // [1,2)
    int idx = (hv >> 14) & 63;
    double t = __hiloint2double(0x3FF00000 | (idx << 14), 0);        // 1+idx/64
    double d = m - t;                                // exact (Sterbenz)
    double f = d * lt[2 * idx];                      // d / t, f in [0, 2^-6)
    double P = __builtin_fma(f, __builtin_fma(f, -0.25, 1.0 / 3.0), -0.5);
    double q = __builtin_fma(f * f, P, f);           // log1p(f), deg 4
    return __builtin_fma((double)E, 0.6931471805599453, lt[2 * idx + 1] + q);
}

// literal reference chain with table primitives (same f32 rounding points).
__device__ __forceinline__ float phi_fast(float xf, const double* lt,
                                          const double* et) {
    xf = fminf(fmaxf(xf, PHI_MIN), PHI_MAX);
    float exf = (float)fast_exp((double)xf, et);
    float af = exf + 1.0f;
    float bf = exf - 1.0f;
    float la = (float)fast_log((double)af, lt);
    float lb = (float)fast_log((double)bf, lt);
    return la - lb;
}

// ---- fused CN kernel, XCD-sharded: one thread per (b, c). ----
template<int FIRST>
__global__ __launch_bounds__(256)
void cn_fused(const float* __restrict__ llr, const float* __restrict__ msgIn,
              float* __restrict__ msgOut)
{
    __shared__ double lt[128];   // (1/t, log t) per 64 mantissa bins
    __shared__ double et[32];    // 2^(j/32)
    {
        int tid = threadIdx.x;
        if (tid < 64) {
            double t = 1.0 + tid * 0.015625;
            double r0 = (double)__builtin_amdgcn_rcpf((float)t);
            r0 = __builtin_fma(__builtin_fma(-t, r0, 1.0), r0, r0);
            r0 = __builtin_fma(__builtin_fma(-t, r0, 1.0), r0, r0);
            lt[2 * tid]     = r0;
            lt[2 * tid + 1] = lean_log(t);
        } else if (tid < 96) {
            int j = tid - 64;
            et[j] = lean_exp(j * EXP_STEP);
        }
    }
    __syncthreads();

    int bid = blockIdx.x;
    int seq = bid >> 3;                          // [0, 512)
    int b   = (bid & 7) * 16 + (seq >> 5);       // 16 batches per XCD
    int c   = (seq & 31) * 256 + threadIdx.x;    // [0, 8192)

    const float* mi = msgIn + (size_t)b * NUM_EDGES;
    float* mo = msgOut + (size_t)b * NUM_EDGES;
    const float* lbp = llr + (size_t)b * NUM_VNS;

    float g[6];                                     // signed mags (sign in bit)
#pragma unroll
    for (int t = 0; t < 6; ++t) {
        int e = c + (t << 13);
        int v = (int)(((unsigned)e * 43691u) >> 17);  // e/3, e < 98304
        float x = fminf(fmaxf(lbp[v], -LLR_MAX), LLR_MAX);
        float m;
        if (FIRST) {
            m = -x;                                   // msgs are all zero
        } else {
            int e0 = 3 * v;
            int j  = e - e0;                          // e mod 3
            float m0 = mi[e0], m1 = mi[e0 + 1], m2 = mi[e0 + 2];
            float s = ((m0 + m1) + m2) - x;           // exact reference order
            float own = (j == 0) ? m0 : ((j == 1) ? m1 : m2);
            m = s - own;                              // vn-extrinsic
        }
        unsigned neg = (m < 0.0f) ? 0x80000000u : 0u; // sign(0) -> +1
        float mg = phi_fast(fabsf(m), lt, et);
        g[t] = __uint_as_float(__float_as_uint(mg) | neg);
    }
    float a0 = fabsf(g[0]), a1 = fabsf(g[1]), a2 = fabsf(g[2]);
    float a3 = fabsf(g[3]), a4 = fabsf(g[4]), a5 = fabsf(g[5]);
    float ms = ((((a0 + a1) + a2) + a3) + a4) + a5;   // reference left-fold
    unsigned all6 = (__float_as_uint(g[0]) ^ __float_as_uint(g[1])
                   ^ __float_as_uint(g[2]) ^ __float_as_uint(g[3])
                   ^ __float_as_uint(g[4]) ^ __float_as_uint(g[5]))
                  & 0x80000000u;
#pragma unroll
    for (int t = 0; t < 6; ++t) {
        int e = c + (t << 13);
        float o = phi_fast(ms - fabsf(g[t]), lt, et);
        unsigned sg = all6 ^ (__float_as_uint(g[t]) & 0x80000000u);
        mo[e] = __uint_as_float(__float_as_uint(o) ^ sg);
    }
}

// ---- final marginalize, XCD-sharded to match cn_fused's batch->XCD map. ----
__global__ __launch_bounds__(256)
void vn_final(const float* __restrict__ llr, const float* __restrict__ msg,
              float* __restrict__ outv)
{
    int bid = blockIdx.x;                        // 8192 blocks
    int seq = bid >> 3;                          // [0, 1024)
    int b   = (bid & 7) * 16 + (seq >> 6);       // 16 batches per XCD
    int v   = (seq & 63) * 256 + threadIdx.x;    // [0, 16384)
    float x = fminf(fmaxf(llr[(size_t)b * NUM_VNS + v], -LLR_MAX), LLR_MAX);
    const float* mb = msg + (size_t)b * NUM_EDGES;
    int e = 3 * v;
    float s = ((mb[e] + mb[e + 1]) + mb[e + 2]) - x;  // exact reference order
    outv[(size_t)b * NUM_VNS + v] = -s;
}

// ---- VN kernel (r12 fallback). ----
template<int FIRST, int LAST>
__global__ __launch_bounds__(256)
void vn_kernel(const float* __restrict__ llr, const float* __restrict__ msg,
               float* __restrict__ outv)
{
    int gid = blockIdx.x * 256 + threadIdx.x;       // b*16384 + v
    int b = gid >> 14;
    int v = gid & 16383;
    float x = fminf(fmaxf(llr[gid], -LLR_MAX), LLR_MAX);
    float s;
    if (FIRST) {
        s = -x;
    } else {
        const float* mb = msg + (size_t)b * NUM_EDGES;
        int e = 3 * v;
        s = ((mb[e] + mb[e + 1]) + mb[e + 2]) - x;
    }
    outv[gid] = LAST ? -s : s;
}

// ---- CN kernel (r12 fallback, reads precomputed vtot). ----
template<int FIRST>
__global__ __launch_bounds__(256)
void cn_kernel(float* __restrict__ msg, const float* __restrict__ vtot)
{
    int gid = blockIdx.x * 256 + threadIdx.x;       // b*8192 + c
    int b = gid >> 13;
    int c = gid & 8191;
    float* mb = msg + (size_t)b * NUM_EDGES;
    const float* vt = vtot + (size_t)b * NUM_VNS;

    float g[6];
#pragma unroll
    for (int t = 0; t < 6; ++t) {
        int e = c + (t << 13);
        int v = (int)(((unsigned)e * 43691u) >> 17);
        float m = FIRST ? vt[v] : (vt[v] - mb[e]);
        unsigned neg = (m < 0.0f) ? 0x80000000u : 0u;
        float mg = phi_f(fabsf(m));
        g[t] = __uint_as_float(__float_as_uint(mg) | neg);
    }
    float a0 = fabsf(g[0]), a1 = fabsf(g[1]), a2 = fabsf(g[2]);
    float a3 = fabsf(g[3]), a4 = fabsf(g[4]), a5 = fabsf(g[5]);
    float ms = ((((a0 + a1) + a2) + a3) + a4) + a5;
    unsigned all6 = (__float_as_uint(g[0]) ^ __float_as_uint(g[1])
                   ^ __float_as_uint(g[2]) ^ __float_as_uint(g[3])
                   ^ __float_as_uint(g[4]) ^ __float_as_uint(g[5]))
                  & 0x80000000u;
#pragma unroll
    for (int t = 0; t < 6; ++t) {
        int e = c + (t << 13);
        float o = phi_f(ms - fabsf(g[t]));
        unsigned sg = all6 ^ (__float_as_uint(g[t]) & 0x80000000u);
        mb[e] = __uint_as_float(__float_as_uint(o) ^ sg);
    }
}

extern "C" void kernel_launch(void* const* d_in, const int* in_sizes, int n_in,
                              void* d_out, int out_size, void* d_ws, size_t ws_size,
                              hipStream_t stream) {
    const float* llr = (const float*)d_in[0];
    float* out = (float*)d_out;

    const int VNB = BATCH * NUM_VNS / 256;             // 8192 blocks
    const int CNB = BATCH * NUM_CNS / 256;             // 4096 blocks
    const size_t MSGSZ = (size_t)BATCH * NUM_EDGES;    // 6.29M floats = 24 MB

    if (ws_size >= 2 * MSGSZ * sizeof(float)) {
        // ---- fused path: 8 CN launches (double-buffered) + final VN ----
        float* buf0 = (float*)d_ws;
        float* buf1 = buf0 + MSGSZ;
        cn_fused<1><<<CNB, 256, 0, stream>>>(llr, buf0, buf0);     // writes buf0
        for (int it = 1; it < NUM_ITER; ++it) {
            float* in  = (it & 1) ? buf0 : buf1;
            float* dst = (it & 1) ? buf1 : buf0;
            cn_fused<0><<<CNB, 256, 0, stream>>>(llr, in, dst);
        }
        // NUM_ITER=8: last write was buf1 (it=7 -> dst=buf1)
        vn_final<<<VNB, 256, 0, stream>>>(llr, buf1, out);
    } else {
        // ---- r12 fallback: 32 MB workspace ----
        float* msg  = (float*)d_ws;
        float* vtot = msg + MSGSZ;
        vn_kernel<1, 0><<<VNB, 256, 0, stream>>>(llr, msg, vtot);
        cn_kernel<1><<<CNB, 256, 0, stream>>>(msg, vtot);
        for (int it = 1; it < NUM_ITER; ++it) {
            vn_kernel<0, 0><<<VNB, 256, 0, stream>>>(llr, msg, vtot);
            cn_kernel<0><<<CNB, 256, 0, stream>>>(msg, vtot);
        }
        vn_kernel<0, 1><<<VNB, 256, 0, stream>>>(llr, msg, out);
    }
}